// Round 4
// baseline (345.342 us; speedup 1.0000x reference)
//
#include <hip/hip_runtime.h>

#define T_STEPS 1024
#define B_DIM   128
#define D_DIM   256
#define H_DIM   256
#define DH      512   // D + H

__device__ __forceinline__ float wave_sum(float v) {
#pragma unroll
    for (int off = 32; off > 0; off >>= 1) v += __shfl_xor(v, off, 64);
    return v;
}

// sigmoid(q) for |q|<=1 (q = sin(...)): Taylor deg-5, err <= 2.2e-4. FMA-only.
__device__ __forceinline__ float sig_poly(float q) {
    float t = q * q;
    float p = fmaf(t, 1.0f / 480.0f, -1.0f / 48.0f);
    p = fmaf(t, p, 0.25f);
    return fmaf(q, p, 0.5f);
}

// tanh(x) Pade(5,4): x(x^4+105x^2+945)/(15x^4+420x^2+945); err<1e-4 for |x|<=2.3.
// |c| provably <= 2.08 (fixed point of f*c+i*g with f,i<=0.731, g<=0.762).
__device__ __forceinline__ float tanh_pade(float x) {
    float t = x * x;
    float n = fmaf(t, t + 105.0f, 945.0f);
    float d = fmaf(t, fmaf(t, 15.0f, 420.0f), 945.0f);
    return x * n * __builtin_amdgcn_rcpf(d);
}

// xdot[row][k] = x[row,:] . W[k,:256] + b[k]   — wave per row, grid-stride
__global__ __launch_bounds__(256) void k_xdot(const float* __restrict__ x,
                                              const float* __restrict__ W,
                                              const float* __restrict__ bias,
                                              float* __restrict__ xdot) {
    const int lane = threadIdx.x & 63;
    const int wid = blockIdx.x * (blockDim.x >> 6) + (threadIdx.x >> 6);
    const int nw = (gridDim.x * blockDim.x) >> 6;
    const int nrows = T_STEPS * B_DIM;

    float4 wk0 = ((const float4*)(W + 0 * DH))[lane];
    float4 wk1 = ((const float4*)(W + 1 * DH))[lane];
    float4 wk2 = ((const float4*)(W + 2 * DH))[lane];
    float4 wk3 = ((const float4*)(W + 3 * DH))[lane];
    const float b0 = bias[0], b1 = bias[1], b2 = bias[2], b3 = bias[3];

    const float4* xv4 = (const float4*)x;  // 64 float4 per row

    int row = wid;
    if (row >= nrows) return;
    float4 xv = xv4[row * 64 + lane];
    for (; row < nrows; row += nw) {
        float4 cur = xv;
        int nrow = row + nw;
        if (nrow < nrows) xv = xv4[nrow * 64 + lane];  // prefetch next row

        float p0 = fmaf(cur.x, wk0.x, fmaf(cur.y, wk0.y, fmaf(cur.z, wk0.z, cur.w * wk0.w)));
        float p1 = fmaf(cur.x, wk1.x, fmaf(cur.y, wk1.y, fmaf(cur.z, wk1.z, cur.w * wk1.w)));
        float p2 = fmaf(cur.x, wk2.x, fmaf(cur.y, wk2.y, fmaf(cur.z, wk2.z, cur.w * wk2.w)));
        float p3 = fmaf(cur.x, wk3.x, fmaf(cur.y, wk3.y, fmaf(cur.z, wk3.z, cur.w * wk3.w)));
        p0 = wave_sum(p0);
        p1 = wave_sum(p1);
        p2 = wave_sum(p2);
        p3 = wave_sum(p3);
        if (lane == 0) {
            float4 r;
            r.x = p0 + b0; r.y = p1 + b1; r.z = p2 + b2; r.w = p3 + b3;
            ((float4*)xdot)[row] = r;
        }
    }
}

// sequential scan: 128 independent chains. Prefetch ring held in 16 NAMED
// float4 variables (no array -> guaranteed VGPR residency; round-3 evidence:
// VGPR_Count=48 proved the array ring was scratch-backed).
// Prefetch reads up to row 1039 (< d_out's 134 MB backing) — never consumed.
__global__ __launch_bounds__(128) void k_scan(const float* __restrict__ xdot,
                                              const float* __restrict__ W,
                                              float* __restrict__ hseq,
                                              float* __restrict__ cfin) {
    const int b = threadIdx.x;  // 0..127
    __shared__ float s_whp[4];
    {   // whp[k] = sum_h W[k, 256+h]; threads (k = b>>5, j = b&31) each sum 8
        int k = b >> 5, j = b & 31;
        const float4* wr = (const float4*)(W + k * DH + D_DIM + j * 8);
        float4 v0 = wr[0], v1 = wr[1];
        float s = (v0.x + v0.y) + (v0.z + v0.w) + (v1.x + v1.y) + (v1.z + v1.w);
#pragma unroll
        for (int off = 16; off > 0; off >>= 1) s += __shfl_xor(s, off, 32);
        if (j == 0) s_whp[k] = s;
    }
    __syncthreads();
    const float w0 = s_whp[0], w1 = s_whp[1], w2 = s_whp[2], w3 = s_whp[3];
    const float4* xr = (const float4*)xdot;  // [t*128 + b]

    float4 r0  = xr[ 0 * B_DIM + b], r1  = xr[ 1 * B_DIM + b];
    float4 r2  = xr[ 2 * B_DIM + b], r3  = xr[ 3 * B_DIM + b];
    float4 r4  = xr[ 4 * B_DIM + b], r5  = xr[ 5 * B_DIM + b];
    float4 r6  = xr[ 6 * B_DIM + b], r7  = xr[ 7 * B_DIM + b];
    float4 r8  = xr[ 8 * B_DIM + b], r9  = xr[ 9 * B_DIM + b];
    float4 r10 = xr[10 * B_DIM + b], r11 = xr[11 * B_DIM + b];
    float4 r12 = xr[12 * B_DIM + b], r13 = xr[13 * B_DIM + b];
    float4 r14 = xr[14 * B_DIM + b], r15 = xr[15 * B_DIM + b];

    float c = 0.0f, h = 0.0f;
    float* hout = hseq + b;

#define STEP(J, R)                                             \
    {                                                          \
        float4 cur = (R);                                      \
        (R) = xr[(tb + 16 + (J)) * B_DIM + b];                 \
        float q0 = __sinf(fmaf(h, w0, cur.x));                 \
        float q1 = __sinf(fmaf(h, w1, cur.y));                 \
        float q2 = __sinf(fmaf(h, w2, cur.z));                 \
        float q3 = __sinf(fmaf(h, w3, cur.w));                 \
        float f = sig_poly(q0);                                \
        float i = sig_poly(q1);                                \
        float g = tanh_pade(q2);                               \
        float o = sig_poly(q3);                                \
        c = fmaf(f, c, i * g);                                 \
        h = o * tanh_pade(c);                                  \
        hout[(tb + (J)) * B_DIM] = h;                          \
    }

    for (int tb = 0; tb < T_STEPS; tb += 16) {
        STEP(0,  r0)  STEP(1,  r1)  STEP(2,  r2)  STEP(3,  r3)
        STEP(4,  r4)  STEP(5,  r5)  STEP(6,  r6)  STEP(7,  r7)
        STEP(8,  r8)  STEP(9,  r9)  STEP(10, r10) STEP(11, r11)
        STEP(12, r12) STEP(13, r13) STEP(14, r14) STEP(15, r15)
    }
#undef STEP
    cfin[b] = c;
}

// broadcast h over H=256 columns; wave per output row of 64 float4s.
// rows: [0,131072) stacked, [131072,131200) hx, [131200,131328) cx
__global__ __launch_bounds__(256) void k_bcast(const float* __restrict__ hseq,
                                               const float* __restrict__ cfin,
                                               float4* __restrict__ out) {
    const int wave = blockIdx.x * (blockDim.x >> 6) + (threadIdx.x >> 6);
    const int lane = threadIdx.x & 63;
    const int NR = T_STEPS * B_DIM;
    if (wave >= NR + 2 * B_DIM) return;
    float v;
    if (wave < NR)               v = hseq[wave];
    else if (wave < NR + B_DIM)  v = hseq[(T_STEPS - 1) * B_DIM + (wave - NR)];
    else                         v = cfin[wave - NR - B_DIM];
    out[(size_t)wave * 64 + lane] = make_float4(v, v, v, v);
}

extern "C" void kernel_launch(void* const* d_in, const int* in_sizes, int n_in,
                              void* d_out, int out_size, void* d_ws, size_t ws_size,
                              hipStream_t stream) {
    const float* x = (const float*)d_in[0];   // (1024,128,256) f32
    const float* W = (const float*)d_in[1];   // (4,512) f32
    const float* b = (const float*)d_in[2];   // (4,) f32
    // d_in[3] = qw — mathematically inert (sin invariant under RX then H)

    float* out = (float*)d_out;

    float* wsf  = (float*)d_ws;
    float* hseq = wsf + 16;                      // 131072 floats
    float* cfin = wsf + 16 + T_STEPS * B_DIM;    // 128 floats
    float* xdot = out;  // 8.5 MB scratch in d_out head (incl. 16-row pad);
                        // d_out is 134 MB and fully overwritten by k_bcast.

    k_xdot<<<2048, 256, 0, stream>>>(x, W, b, xdot);
    k_scan<<<1, 128, 0, stream>>>(xdot, W, hseq, cfin);

    const int rows = T_STEPS * B_DIM + 2 * B_DIM;          // 131328
    k_bcast<<<(rows + 3) / 4, 256, 0, stream>>>(hseq, cfin, (float4*)out);
}

// Round 5
// 345.287 us; speedup vs baseline: 1.0002x; 1.0002x over previous
//
#include <hip/hip_runtime.h>

#define T_STEPS 1024
#define B_DIM   128
#define D_DIM   256
#define H_DIM   256
#define DH      512   // D + H

__device__ __forceinline__ float wave_sum(float v) {
#pragma unroll
    for (int off = 32; off > 0; off >>= 1) v += __shfl_xor(v, off, 64);
    return v;
}

// sigmoid(q) for |q|<=1 (q = sin(...)): Taylor deg-5, err <= 2.2e-4. FMA-only.
__device__ __forceinline__ float sig_poly(float q) {
    float t = q * q;
    float p = fmaf(t, 1.0f / 480.0f, -1.0f / 48.0f);
    p = fmaf(t, p, 0.25f);
    return fmaf(q, p, 0.5f);
}

// tanh(x) Pade(5,4): x(x^4+105x^2+945)/(15x^4+420x^2+945); err<1e-4 for |x|<=2.3.
// |c| provably <= 2.08 (fixed point of f*c+i*g with f,i<=0.731, g<=0.762).
__device__ __forceinline__ float tanh_pade(float x) {
    float t = x * x;
    float n = fmaf(t, t + 105.0f, 945.0f);
    float d = fmaf(t, fmaf(t, 15.0f, 420.0f), 945.0f);
    return x * n * __builtin_amdgcn_rcpf(d);
}

// xdot[row][k] = x[row,:] . W[k,:256] + b[k]   — wave per row, grid-stride
__global__ __launch_bounds__(256) void k_xdot(const float* __restrict__ x,
                                              const float* __restrict__ W,
                                              const float* __restrict__ bias,
                                              float* __restrict__ xdot) {
    const int lane = threadIdx.x & 63;
    const int wid = blockIdx.x * (blockDim.x >> 6) + (threadIdx.x >> 6);
    const int nw = (gridDim.x * blockDim.x) >> 6;
    const int nrows = T_STEPS * B_DIM;

    float4 wk0 = ((const float4*)(W + 0 * DH))[lane];
    float4 wk1 = ((const float4*)(W + 1 * DH))[lane];
    float4 wk2 = ((const float4*)(W + 2 * DH))[lane];
    float4 wk3 = ((const float4*)(W + 3 * DH))[lane];
    const float b0 = bias[0], b1 = bias[1], b2 = bias[2], b3 = bias[3];

    const float4* xv4 = (const float4*)x;  // 64 float4 per row

    int row = wid;
    if (row >= nrows) return;
    float4 xv = xv4[row * 64 + lane];
    for (; row < nrows; row += nw) {
        float4 cur = xv;
        int nrow = row + nw;
        if (nrow < nrows) xv = xv4[nrow * 64 + lane];  // prefetch next row

        float p0 = fmaf(cur.x, wk0.x, fmaf(cur.y, wk0.y, fmaf(cur.z, wk0.z, cur.w * wk0.w)));
        float p1 = fmaf(cur.x, wk1.x, fmaf(cur.y, wk1.y, fmaf(cur.z, wk1.z, cur.w * wk1.w)));
        float p2 = fmaf(cur.x, wk2.x, fmaf(cur.y, wk2.y, fmaf(cur.z, wk2.z, cur.w * wk2.w)));
        float p3 = fmaf(cur.x, wk3.x, fmaf(cur.y, wk3.y, fmaf(cur.z, wk3.z, cur.w * wk3.w)));
        p0 = wave_sum(p0);
        p1 = wave_sum(p1);
        p2 = wave_sum(p2);
        p3 = wave_sum(p3);
        if (lane == 0) {
            float4 r;
            r.x = p0 + b0; r.y = p1 + b1; r.z = p2 + b2; r.w = p3 + b3;
            ((float4*)xdot)[row] = r;
        }
    }
}

// sequential scan: 128 independent chains. Named 16-deep float4 prefetch ring.
// __launch_bounds__(128, 1): waves-per-eu=1 lifts the default 64-VGPR
// occupancy cap (round-4 evidence: VGPR_Count pinned at 64 = ring spilled).
// Prefetch reads up to row 1039 (< d_out's 134 MB backing) — never consumed.
__global__ __launch_bounds__(128, 1) void k_scan(const float* __restrict__ xdot,
                                                 const float* __restrict__ W,
                                                 float* __restrict__ hseq,
                                                 float* __restrict__ cfin) {
    const int b = threadIdx.x;  // 0..127
    __shared__ float s_whp[4];
    {   // whp[k] = sum_h W[k, 256+h]; threads (k = b>>5, j = b&31) each sum 8
        int k = b >> 5, j = b & 31;
        const float4* wr = (const float4*)(W + k * DH + D_DIM + j * 8);
        float4 v0 = wr[0], v1 = wr[1];
        float s = (v0.x + v0.y) + (v0.z + v0.w) + (v1.x + v1.y) + (v1.z + v1.w);
#pragma unroll
        for (int off = 16; off > 0; off >>= 1) s += __shfl_xor(s, off, 32);
        if (j == 0) s_whp[k] = s;
    }
    __syncthreads();
    const float w0 = s_whp[0], w1 = s_whp[1], w2 = s_whp[2], w3 = s_whp[3];
    const float4* xr = (const float4*)xdot;  // [t*128 + b]

    float4 r0  = xr[ 0 * B_DIM + b], r1  = xr[ 1 * B_DIM + b];
    float4 r2  = xr[ 2 * B_DIM + b], r3  = xr[ 3 * B_DIM + b];
    float4 r4  = xr[ 4 * B_DIM + b], r5  = xr[ 5 * B_DIM + b];
    float4 r6  = xr[ 6 * B_DIM + b], r7  = xr[ 7 * B_DIM + b];
    float4 r8  = xr[ 8 * B_DIM + b], r9  = xr[ 9 * B_DIM + b];
    float4 r10 = xr[10 * B_DIM + b], r11 = xr[11 * B_DIM + b];
    float4 r12 = xr[12 * B_DIM + b], r13 = xr[13 * B_DIM + b];
    float4 r14 = xr[14 * B_DIM + b], r15 = xr[15 * B_DIM + b];

    float c = 0.0f, h = 0.0f;
    float* hout = hseq + b;

#define STEP(J, R)                                             \
    {                                                          \
        float4 cur = (R);                                      \
        (R) = xr[(tb + 16 + (J)) * B_DIM + b];                 \
        float q0 = __sinf(fmaf(h, w0, cur.x));                 \
        float q1 = __sinf(fmaf(h, w1, cur.y));                 \
        float q2 = __sinf(fmaf(h, w2, cur.z));                 \
        float q3 = __sinf(fmaf(h, w3, cur.w));                 \
        float f = sig_poly(q0);                                \
        float i = sig_poly(q1);                                \
        float g = tanh_pade(q2);                               \
        float o = sig_poly(q3);                                \
        c = fmaf(f, c, i * g);                                 \
        h = o * tanh_pade(c);                                  \
        hout[(tb + (J)) * B_DIM] = h;                          \
    }

    for (int tb = 0; tb < T_STEPS; tb += 16) {
        STEP(0,  r0)  STEP(1,  r1)  STEP(2,  r2)  STEP(3,  r3)
        STEP(4,  r4)  STEP(5,  r5)  STEP(6,  r6)  STEP(7,  r7)
        STEP(8,  r8)  STEP(9,  r9)  STEP(10, r10) STEP(11, r11)
        STEP(12, r12) STEP(13, r13) STEP(14, r14) STEP(15, r15)
    }
#undef STEP
    cfin[b] = c;
}

// broadcast h over H=256 columns; wave per output row of 64 float4s.
// rows: [0,131072) stacked, [131072,131200) hx, [131200,131328) cx
__global__ __launch_bounds__(256) void k_bcast(const float* __restrict__ hseq,
                                               const float* __restrict__ cfin,
                                               float4* __restrict__ out) {
    const int wave = blockIdx.x * (blockDim.x >> 6) + (threadIdx.x >> 6);
    const int lane = threadIdx.x & 63;
    const int NR = T_STEPS * B_DIM;
    if (wave >= NR + 2 * B_DIM) return;
    float v;
    if (wave < NR)               v = hseq[wave];
    else if (wave < NR + B_DIM)  v = hseq[(T_STEPS - 1) * B_DIM + (wave - NR)];
    else                         v = cfin[wave - NR - B_DIM];
    out[(size_t)wave * 64 + lane] = make_float4(v, v, v, v);
}

extern "C" void kernel_launch(void* const* d_in, const int* in_sizes, int n_in,
                              void* d_out, int out_size, void* d_ws, size_t ws_size,
                              hipStream_t stream) {
    const float* x = (const float*)d_in[0];   // (1024,128,256) f32
    const float* W = (const float*)d_in[1];   // (4,512) f32
    const float* b = (const float*)d_in[2];   // (4,) f32
    // d_in[3] = qw — mathematically inert (sin invariant under RX then H)

    float* out = (float*)d_out;

    float* wsf  = (float*)d_ws;
    float* hseq = wsf + 16;                      // 131072 floats
    float* cfin = wsf + 16 + T_STEPS * B_DIM;    // 128 floats
    float* xdot = out;  // 8.5 MB scratch in d_out head (incl. 16-row pad);
                        // d_out is 134 MB and fully overwritten by k_bcast.

    k_xdot<<<2048, 256, 0, stream>>>(x, W, b, xdot);
    k_scan<<<1, 128, 0, stream>>>(xdot, W, hseq, cfin);

    const int rows = T_STEPS * B_DIM + 2 * B_DIM;          // 131328
    k_bcast<<<(rows + 3) / 4, 256, 0, stream>>>(hseq, cfin, (float4*)out);
}

// Round 6
// 340.664 us; speedup vs baseline: 1.0137x; 1.0136x over previous
//
#include <hip/hip_runtime.h>

#define T_STEPS 1024
#define B_DIM   128
#define D_DIM   256
#define H_DIM   256
#define DH      512   // D + H

__device__ __forceinline__ float wave_sum(float v) {
#pragma unroll
    for (int off = 32; off > 0; off >>= 1) v += __shfl_xor(v, off, 64);
    return v;
}

// sigmoid(q) for |q|<=1 (q = sin(...)): Taylor deg-5, err <= 2.2e-4. FMA-only.
__device__ __forceinline__ float sig_poly(float q) {
    float t = q * q;
    float p = fmaf(t, 1.0f / 480.0f, -1.0f / 48.0f);
    p = fmaf(t, p, 0.25f);
    return fmaf(q, p, 0.5f);
}

// tanh(x) Pade(5,4): err<1e-4 for |x|<=2.3; |c| provably <= 2.08.
__device__ __forceinline__ float tanh_pade(float x) {
    float t = x * x;
    float n = fmaf(t, t + 105.0f, 945.0f);
    float d = fmaf(t, fmaf(t, 15.0f, 420.0f), 945.0f);
    return x * n * __builtin_amdgcn_rcpf(d);
}

// xdot[row][k] = x[row,:] . W[k,:256] + b[k]   — wave per row, grid-stride
__global__ __launch_bounds__(256) void k_xdot(const float* __restrict__ x,
                                              const float* __restrict__ W,
                                              const float* __restrict__ bias,
                                              float* __restrict__ xdot) {
    const int lane = threadIdx.x & 63;
    const int wid = blockIdx.x * (blockDim.x >> 6) + (threadIdx.x >> 6);
    const int nw = (gridDim.x * blockDim.x) >> 6;
    const int nrows = T_STEPS * B_DIM;

    float4 wk0 = ((const float4*)(W + 0 * DH))[lane];
    float4 wk1 = ((const float4*)(W + 1 * DH))[lane];
    float4 wk2 = ((const float4*)(W + 2 * DH))[lane];
    float4 wk3 = ((const float4*)(W + 3 * DH))[lane];
    const float b0 = bias[0], b1 = bias[1], b2 = bias[2], b3 = bias[3];

    const float4* xv4 = (const float4*)x;  // 64 float4 per row

    int row = wid;
    if (row >= nrows) return;
    float4 xv = xv4[row * 64 + lane];
    for (; row < nrows; row += nw) {
        float4 cur = xv;
        int nrow = row + nw;
        if (nrow < nrows) xv = xv4[nrow * 64 + lane];  // prefetch next row

        float p0 = fmaf(cur.x, wk0.x, fmaf(cur.y, wk0.y, fmaf(cur.z, wk0.z, cur.w * wk0.w)));
        float p1 = fmaf(cur.x, wk1.x, fmaf(cur.y, wk1.y, fmaf(cur.z, wk1.z, cur.w * wk1.w)));
        float p2 = fmaf(cur.x, wk2.x, fmaf(cur.y, wk2.y, fmaf(cur.z, wk2.z, cur.w * wk2.w)));
        float p3 = fmaf(cur.x, wk3.x, fmaf(cur.y, wk3.y, fmaf(cur.z, wk3.z, cur.w * wk3.w)));
        p0 = wave_sum(p0);
        p1 = wave_sum(p1);
        p2 = wave_sum(p2);
        p3 = wave_sum(p3);
        if (lane == 0) {
            float4 r;
            r.x = p0 + b0; r.y = p1 + b1; r.z = p2 + b2; r.w = p3 + b3;
            ((float4*)xdot)[row] = r;
        }
    }
}

// sequential scan, 128 chains. Software pipeline implemented in INLINE ASM:
// round-5 evidence showed the pre-RA scheduler sinks C-level prefetch loads
// to just before use (VGPR pinned at 64, 255 cyc/step = exposed L3 latency).
// asm volatile loads + explicit s_waitcnt vmcnt(32) make sinking impossible.
// All loop memory ops go through asm so the vmcnt event stream is exact:
// per half-block: 16 loads + 16 stores; vmcnt(32) drains the previous ring's
// 16 loads (+ older stores) while leaving the just-issued 16 in flight.
// Prefetch reads up to row 1039 — padded backing in d_out, never consumed.
__global__ __launch_bounds__(128, 1) void k_scan(const float* __restrict__ xdot,
                                                 const float* __restrict__ W,
                                                 float* __restrict__ hseq,
                                                 float* __restrict__ cfin,
                                                 float* __restrict__ dummy) {
    const int b = threadIdx.x;  // 0..127
    __shared__ float s_whp[4];
    {   // whp[k] = sum_h W[k, 256+h]
        int k = b >> 5, j = b & 31;
        const float4* wr = (const float4*)(W + k * DH + D_DIM + j * 8);
        float4 v0 = wr[0], v1 = wr[1];
        float s = (v0.x + v0.y) + (v0.z + v0.w) + (v1.x + v1.y) + (v1.z + v1.w);
#pragma unroll
        for (int off = 16; off > 0; off >>= 1) s += __shfl_xor(s, off, 32);
        if (j == 0) s_whp[k] = s;
    }
    __syncthreads();   // drains all preamble memory ops (vmcnt(0) before barrier)
    const float w0 = s_whp[0], w1 = s_whp[1], w2 = s_whp[2], w3 = s_whp[3];
    const float4* xr = (const float4*)xdot;  // [t*128 + b]

#define LOADQ(R, T) asm volatile("global_load_dwordx4 %0, %1, off" \
                                 : "=v"(R) : "v"(xr + (size_t)(T) * B_DIM + b) : "memory")
#define WAIT32()    asm volatile("s_waitcnt vmcnt(32)" ::: "memory")

    float4 A0, A1, A2, A3, A4, A5, A6, A7, A8, A9, A10, A11, A12, A13, A14, A15;
    float4 C0, C1, C2, C3, C4, C5, C6, C7, C8, C9, C10, C11, C12, C13, C14, C15;

    // prologue: ring A <- rows 0..15, then 16 dummy stores to prime vmcnt
    LOADQ(A0, 0);  LOADQ(A1, 1);  LOADQ(A2, 2);  LOADQ(A3, 3);
    LOADQ(A4, 4);  LOADQ(A5, 5);  LOADQ(A6, 6);  LOADQ(A7, 7);
    LOADQ(A8, 8);  LOADQ(A9, 9);  LOADQ(A10, 10); LOADQ(A11, 11);
    LOADQ(A12, 12); LOADQ(A13, 13); LOADQ(A14, 14); LOADQ(A15, 15);
    {
        float zf = 0.0f;
#pragma unroll
        for (int j = 0; j < 16; ++j)
            asm volatile("global_store_dword %0, %1, off"
                         :: "v"(dummy + j * B_DIM + b), "v"(zf) : "memory");
    }

    float c = 0.0f, h = 0.0f;

#define STEP(T, R)                                                  \
    {                                                               \
        float4 cur = (R);                                           \
        float q0 = __sinf(fmaf(h, w0, cur.x));                      \
        float q1 = __sinf(fmaf(h, w1, cur.y));                      \
        float q2 = __sinf(fmaf(h, w2, cur.z));                      \
        float q3 = __sinf(fmaf(h, w3, cur.w));                      \
        float f = sig_poly(q0);                                     \
        float i = sig_poly(q1);                                     \
        float g = tanh_pade(q2);                                    \
        float o = sig_poly(q3);                                     \
        c = fmaf(f, c, i * g);                                      \
        h = o * tanh_pade(c);                                       \
        asm volatile("global_store_dword %0, %1, off"               \
                     :: "v"(hseq + (size_t)(T) * B_DIM + b), "v"(h) \
                     : "memory");                                   \
    }

    for (int tb = 0; tb < T_STEPS; tb += 32) {
        // issue ring C <- rows tb+16 .. tb+31
        LOADQ(C0, tb + 16); LOADQ(C1, tb + 17); LOADQ(C2, tb + 18); LOADQ(C3, tb + 19);
        LOADQ(C4, tb + 20); LOADQ(C5, tb + 21); LOADQ(C6, tb + 22); LOADQ(C7, tb + 23);
        LOADQ(C8, tb + 24); LOADQ(C9, tb + 25); LOADQ(C10, tb + 26); LOADQ(C11, tb + 27);
        LOADQ(C12, tb + 28); LOADQ(C13, tb + 29); LOADQ(C14, tb + 30); LOADQ(C15, tb + 31);
        WAIT32();  // ring A (rows tb..tb+15) complete; ring C stays in flight
        STEP(tb + 0,  A0)  STEP(tb + 1,  A1)  STEP(tb + 2,  A2)  STEP(tb + 3,  A3)
        STEP(tb + 4,  A4)  STEP(tb + 5,  A5)  STEP(tb + 6,  A6)  STEP(tb + 7,  A7)
        STEP(tb + 8,  A8)  STEP(tb + 9,  A9)  STEP(tb + 10, A10) STEP(tb + 11, A11)
        STEP(tb + 12, A12) STEP(tb + 13, A13) STEP(tb + 14, A14) STEP(tb + 15, A15)
        // issue ring A <- rows tb+32 .. tb+47 (last iter: padded rows 1024..1039)
        LOADQ(A0, tb + 32); LOADQ(A1, tb + 33); LOADQ(A2, tb + 34); LOADQ(A3, tb + 35);
        LOADQ(A4, tb + 36); LOADQ(A5, tb + 37); LOADQ(A6, tb + 38); LOADQ(A7, tb + 39);
        LOADQ(A8, tb + 40); LOADQ(A9, tb + 41); LOADQ(A10, tb + 42); LOADQ(A11, tb + 43);
        LOADQ(A12, tb + 44); LOADQ(A13, tb + 45); LOADQ(A14, tb + 46); LOADQ(A15, tb + 47);
        WAIT32();  // ring C complete; new ring A stays in flight
        STEP(tb + 16, C0)  STEP(tb + 17, C1)  STEP(tb + 18, C2)  STEP(tb + 19, C3)
        STEP(tb + 20, C4)  STEP(tb + 21, C5)  STEP(tb + 22, C6)  STEP(tb + 23, C7)
        STEP(tb + 24, C8)  STEP(tb + 25, C9)  STEP(tb + 26, C10) STEP(tb + 27, C11)
        STEP(tb + 28, C12) STEP(tb + 29, C13) STEP(tb + 30, C14) STEP(tb + 31, C15)
    }
#undef STEP
#undef LOADQ
#undef WAIT32
    cfin[b] = c;
    asm volatile("s_waitcnt vmcnt(0)" ::: "memory");  // asm stores visible to k_bcast
}

// broadcast h over H=256 columns; wave per output row of 64 float4s.
__global__ __launch_bounds__(256) void k_bcast(const float* __restrict__ hseq,
                                               const float* __restrict__ cfin,
                                               float4* __restrict__ out) {
    const int wave = blockIdx.x * (blockDim.x >> 6) + (threadIdx.x >> 6);
    const int lane = threadIdx.x & 63;
    const int NR = T_STEPS * B_DIM;
    if (wave >= NR + 2 * B_DIM) return;
    float v;
    if (wave < NR)               v = hseq[wave];
    else if (wave < NR + B_DIM)  v = hseq[(T_STEPS - 1) * B_DIM + (wave - NR)];
    else                         v = cfin[wave - NR - B_DIM];
    out[(size_t)wave * 64 + lane] = make_float4(v, v, v, v);
}

extern "C" void kernel_launch(void* const* d_in, const int* in_sizes, int n_in,
                              void* d_out, int out_size, void* d_ws, size_t ws_size,
                              hipStream_t stream) {
    const float* x = (const float*)d_in[0];   // (1024,128,256) f32
    const float* W = (const float*)d_in[1];   // (4,512) f32
    const float* b = (const float*)d_in[2];   // (4,) f32
    // d_in[3] = qw — mathematically inert (sin invariant under RX then H)

    float* out = (float*)d_out;

    float* wsf  = (float*)d_ws;
    float* hseq = wsf + 16;                      // 131072 floats
    float* cfin = wsf + 16 + T_STEPS * B_DIM;    // 128 floats
    float* xdot = out;       // 8.5 MB scratch in d_out head (incl. 16-row pad)
    float* dummy = out + (8u << 20);  // dead scratch, overwritten by k_bcast

    k_xdot<<<2048, 256, 0, stream>>>(x, W, b, xdot);
    k_scan<<<1, 128, 0, stream>>>(xdot, W, hseq, cfin, dummy);

    const int rows = T_STEPS * B_DIM + 2 * B_DIM;          // 131328
    k_bcast<<<(rows + 3) / 4, 256, 0, stream>>>(hseq, cfin, (float4*)out);
}